// Round 10
// baseline (124.993 us; speedup 1.0000x reference)
//
#include <hip/hip_runtime.h>
#include <hip/hip_bf16.h>
#include <stdint.h>

// ---------------------------------------------------------------------------
// SNN: x[512,784] -> FC(784->1024)+LIF -> FC(1024->1024)+LIF -> FC(1024->10)+LIF
// T=32, tau=2, vth=1, hard reset. Out = spike counts [512,10].
//
// Verified (R5-R9, absmax=0): layer-0 LIF exactly periodic (class=ctz+1);
// layer-1 current = divisor sum over class weight-sums; cur0 = exact 3-way
// bf16-split (6 cross-terms) MFMA GEMM, split-K x10 for occupancy.
//
// R9 lesson: harness floor ~78us (fill 41 + restores/poisons, from R8's
// single-kernel calibration); controllable budget was ~40us across 5 kernels
// + 4 gaps (~2us/launch). Only ONE grid-wide dependency exists (split-K
// partials -> per-batch LIF), so collapse to 2 kernels:
//   gemm0t_k: split-K MFMA with INLINE fp32->bf16 split staging (bit-identical
//             LDS contents to the prep path) + W1-transpose blocks.
//   tail_k:   compact0+layer1+layer2 fused per batch, lists in LDS; layer-1
//             divisor/segment code preserved verbatim (5x-verified black box).
// ---------------------------------------------------------------------------

typedef __bf16 bf16x8 __attribute__((ext_vector_type(8)));
typedef float  f32x4  __attribute__((ext_vector_type(4)));
typedef unsigned short u16x8 __attribute__((ext_vector_type(8)));

// bf16 component select: 0 -> h, 1 -> m = bf16(v-h), 2 -> l = bf16(v-h-m).
// sel is wave-uniform (branch cheap). Identical arithmetic to R9's bsplit3.
__device__ __forceinline__ unsigned short csel(float v, int sel) {
  __hip_bfloat16 h = __float2bfloat16(v);
  if (sel == 0) return __builtin_bit_cast(unsigned short, h);
  float r1 = v - __bfloat162float(h);
  __hip_bfloat16 m = __float2bfloat16(r1);
  if (sel == 1) return __builtin_bit_cast(unsigned short, m);
  float r2 = r1 - __bfloat162float(m);
  __hip_bfloat16 l = __float2bfloat16(r2);
  return __builtin_bit_cast(unsigned short, l);
}

// ---------------- kernel 1: split-K MFMA GEMM (inline split) + W1 transpose -
// Blocks [0,320): gemm, decode bx(4) x by(8) x bz(10). Blocks [320,1344):
// W1 32x32 transpose tiles. Segment s = kk/800 is uniform per BK=32 iter
// (800 % 32 == 0). A comps {h,h,m,m,h,l}[s], B comps {h,m,h,m,l,h}[s].
// LDS writer reproduces the old gload16 swizzle: logical 16B group g of
// local row r -> physical group g ^ ((r>>1)&3); per thread (row r, half h)
// that is the 32B-aligned pair base 32*(h ^ ((r>>2)&1)), halves swapped
// when (r>>1)&1. Reader (quad ^ swz) unchanged -> bit-identical Cpart.
__global__ __launch_bounds__(256, 2) void gemm0t_k(const float* __restrict__ x,
                                                   const float* __restrict__ W0,
                                                   const float* __restrict__ W1,
                                                   float* __restrict__ W1T,
                                                   float* __restrict__ Cpart) {
  __shared__ __align__(16) char smem[16512];
  const int bid = blockIdx.x, tid = threadIdx.x;

  if (bid >= 320) {                       // ---- W1 transpose tiles ----
    float (*t)[33] = (float(*)[33])smem;
    int tt = bid - 320;
    int c0 = (tt & 31) * 32, r0 = (tt >> 5) * 32;
    int lx = tid & 31, ly = tid >> 5;     // 32 x 8
#pragma unroll
    for (int i = 0; i < 32; i += 8)
      t[ly + i][lx] = W1[(size_t)(r0 + ly + i) * 1024 + (c0 + lx)];
    __syncthreads();
#pragma unroll
    for (int i = 0; i < 32; i += 8)
      W1T[(size_t)(c0 + ly + i) * 1024 + (r0 + lx)] = t[lx][ly + i];
    return;
  }

  // ---- gemm blocks ----
  const int bx = bid & 3, by = (bid >> 2) & 7, bz = bid >> 5;
  const int wave = tid >> 6, lane = tid & 63, quad = lane >> 4, l16 = lane & 15;
  const int wm = (wave >> 1) * 64, wn = (wave & 1) * 64;
  const int mbase = bx * 128, nbase = by * 128, kbase = bz * 480;
  const int swz = (l16 >> 1) & 3;

  // staging role: row r (0..127), col-half h (16 cols each)
  const int r = tid >> 1, h = tid & 1;
  const int sw = (r >> 1) & 3;
  const int swap = sw & 1;
  char* adst = smem + r * 64 + 32 * (h ^ (sw >> 1));
  char* bdst = smem + 8192 + r * 64 + 32 * (h ^ (sw >> 1));
  const float* xr = x + (size_t)(mbase + r) * 784;
  const float* wr = W0 + (size_t)(nbase + r) * 784;

  f32x4 acc[4][4] = {};

  for (int kk = kbase; kk < kbase + 480; kk += 32) {
    const int s = kk / 800;                        // uniform per iter
    const int k0 = kk - s * 800 + h * 16;          // this thread's col base
    const int selA = (s == 2 || s == 3) ? 1 : ((s == 5) ? 2 : 0);
    const int selB = (s == 1 || s == 3) ? 1 : ((s == 4) ? 2 : 0);
    {
      float v[16];
#pragma unroll
      for (int q = 0; q < 4; ++q) {
        int kq = k0 + q * 4;
        if (kq < 784) {
          f32x4 t4 = *(const f32x4*)(xr + kq);
          v[q*4+0] = t4[0]; v[q*4+1] = t4[1]; v[q*4+2] = t4[2]; v[q*4+3] = t4[3];
        } else {
          v[q*4+0] = 0.f; v[q*4+1] = 0.f; v[q*4+2] = 0.f; v[q*4+3] = 0.f;
        }
      }
      u16x8 c0v, c1v;
#pragma unroll
      for (int j = 0; j < 8; ++j) c0v[j] = csel(v[j], selA);
#pragma unroll
      for (int j = 0; j < 8; ++j) c1v[j] = csel(v[8 + j], selA);
      *(u16x8*)(adst + (swap ? 16 : 0)) = c0v;
      *(u16x8*)(adst + (swap ? 0 : 16)) = c1v;
    }
    {
      float v[16];
#pragma unroll
      for (int q = 0; q < 4; ++q) {
        int kq = k0 + q * 4;
        if (kq < 784) {
          f32x4 t4 = *(const f32x4*)(wr + kq);
          v[q*4+0] = t4[0]; v[q*4+1] = t4[1]; v[q*4+2] = t4[2]; v[q*4+3] = t4[3];
        } else {
          v[q*4+0] = 0.f; v[q*4+1] = 0.f; v[q*4+2] = 0.f; v[q*4+3] = 0.f;
        }
      }
      u16x8 c0v, c1v;
#pragma unroll
      for (int j = 0; j < 8; ++j) c0v[j] = csel(v[j], selB);
#pragma unroll
      for (int j = 0; j < 8; ++j) c1v[j] = csel(v[8 + j], selB);
      *(u16x8*)(bdst + (swap ? 16 : 0)) = c0v;
      *(u16x8*)(bdst + (swap ? 0 : 16)) = c1v;
    }
    __syncthreads();

    const __bf16* Ab = (const __bf16*)smem;
    const __bf16* Bb = Ab + 128 * 32;
    bf16x8 af[4], bfr[4];
#pragma unroll
    for (int i = 0; i < 4; ++i)
      af[i] = *(const bf16x8*)(Ab + (wm + i * 16 + l16) * 32 + ((quad ^ swz) * 8));
#pragma unroll
    for (int j = 0; j < 4; ++j)
      bfr[j] = *(const bf16x8*)(Bb + (wn + j * 16 + l16) * 32 + ((quad ^ swz) * 8));
#pragma unroll
    for (int i = 0; i < 4; ++i)
#pragma unroll
      for (int j = 0; j < 4; ++j)
        acc[i][j] = __builtin_amdgcn_mfma_f32_16x16x32_bf16(af[i], bfr[j], acc[i][j], 0, 0, 0);
    __syncthreads();
  }

  float* Cz = Cpart + (size_t)bz * 512 * 1024;
#pragma unroll
  for (int i = 0; i < 4; ++i)
#pragma unroll
    for (int j = 0; j < 4; ++j)
#pragma unroll
      for (int rr = 0; rr < 4; ++rr) {
        int m = mbase + wm + i * 16 + quad * 4 + rr;
        int n = nbase + wn + j * 16 + l16;
        Cz[(size_t)m * 1024 + n] = acc[i][j][rr];
      }
}

// ---------------- kernel 2: fused tail (compact0 + layer1 + layer2) ---------
// One block per batch, 1024 threads. All inter-stage data in LDS.
struct TailSM {
  unsigned short sidx[1024];
  int sseg[33];
  int mtot;
  unsigned l2i[1024];
  unsigned l2w[1024];
  union {
    struct { int whist[16][33]; int clstot[33]; int clsofs[34]; int wofs[16][33]; } s3;
    struct { int wtot[16]; int wbase[16]; } s4;
    struct { float sW2[10 * 1025]; float scur[320]; } s5;
  } u;
};

__global__ __launch_bounds__(1024) void tail_k(const float* __restrict__ Cpart,
                                               const float* __restrict__ b0,
                                               const float* __restrict__ W1T,
                                               const float* __restrict__ b1,
                                               const float* __restrict__ W2,
                                               const float* __restrict__ b2,
                                               float* __restrict__ out) {
  __shared__ TailSM sm;
  const int b = blockIdx.x, o = threadIdx.x;
  const int wave = o >> 6, lane = o & 63;

  // ---- S3: split-K reduce + LIF + class compaction (R9 compact0_k verbatim)
  {
    float cur = 0.f;
#pragma unroll
    for (int z = 0; z < 10; ++z)
      cur += Cpart[(size_t)z * 512 * 1024 + (size_t)b * 1024 + o];
    cur += b0[o];
    float v = 0.f;
    unsigned word = 0u;
#pragma unroll
    for (int t = 0; t < 32; ++t) {
      v = v + (cur - v) * 0.5f;            // exact: /2.0 == *0.5f
      if (v >= 1.0f) { word |= 1u << t; v = 0.f; }
    }
    int n = word ? (__builtin_ctz(word) + 1) : 0;
    unsigned long long mymask = 0ull;
#pragma unroll 1
    for (int c = 1; c <= 32; ++c) {
      unsigned long long m = __ballot(n == c);
      if (lane == 0) sm.u.s3.whist[wave][c] = __popcll(m);
      if (n == c) mymask = m;
    }
    __syncthreads();
    if (o < 32) {
      int c = o + 1, s = 0;
#pragma unroll
      for (int w = 0; w < 16; ++w) s += sm.u.s3.whist[w][c];
      sm.u.s3.clstot[c] = s;
    }
    __syncthreads();
    if (o == 0) {
      int run = 0;
#pragma unroll
      for (int c = 1; c <= 32; ++c) { sm.u.s3.clsofs[c] = run; run += sm.u.s3.clstot[c]; }
      sm.u.s3.clsofs[33] = run;
    }
    __syncthreads();
    if (o < 32) {
      int c = o + 1, s = sm.u.s3.clsofs[c];
#pragma unroll
      for (int w = 0; w < 16; ++w) { sm.u.s3.wofs[w][c] = s; s += sm.u.s3.whist[w][c]; }
    }
    __syncthreads();
    if (n) {
      int pos = sm.u.s3.wofs[wave][n] + __popcll(mymask & ((1ull << lane) - 1ull));
      sm.sidx[pos] = (unsigned short)o;
    }
    if (o < 33) sm.sseg[o] = sm.u.s3.clsofs[o + 1];
  }
  __syncthreads();

  // ---- S4: layer-1 class-sums + divisor LIF + compaction (R9 layer1_k,
  //          tid-direct over 1024 outputs; identical order/arithmetic)
  {
    float S[32];
#pragma unroll
    for (int c = 0; c < 32; ++c) {
      int j0 = __builtin_amdgcn_readfirstlane((c == 0) ? 0 : sm.sseg[c - 1]);
      int j1 = __builtin_amdgcn_readfirstlane(sm.sseg[c]);
      float s = 0.f;
      for (int j = j0; j < j1; ++j)
        s += W1T[(size_t)sm.sidx[j] * 1024 + o];
      S[c] = s;
    }
    const float bias = b1[o];
    float v = 0.f;
    unsigned word = 0u;
#pragma unroll
    for (int t = 0; t < 32; ++t) {
      float cur = 0.f;
#pragma unroll
      for (int c = 1; c <= 32; ++c)
        if ((t + 1) % c == 0) cur += S[c - 1];   // compile-time divisor table
      float xc = cur + bias;
      v = v + (xc - v) * 0.5f;
      if (v >= 1.0f) { word |= 1u << t; v = 0.f; }
    }
    bool act = (word != 0u);
    unsigned long long m = __ballot(act);
    if (lane == 0) sm.u.s4.wtot[wave] = __popcll(m);
    __syncthreads();
    if (o == 0) {
      int s = 0;
#pragma unroll
      for (int i = 0; i < 16; ++i) { sm.u.s4.wbase[i] = s; s += sm.u.s4.wtot[i]; }
      sm.mtot = s;
    }
    __syncthreads();
    if (act) {
      int pos = sm.u.s4.wbase[wave] + __popcll(m & ((1ull << lane) - 1ull));
      sm.l2i[pos] = (unsigned)o;
      sm.l2w[pos] = word;
    }
  }
  __syncthreads();

  // ---- S5: layer-2 sparse FC + LIF + count (R7/R9 layer2_k arithmetic) ----
  {
    for (int i = o; i < 10240; i += 1024)
      sm.u.s5.sW2[(i >> 10) * 1025 + (i & 1023)] = W2[i];
    __syncthreads();
    const int mtot = sm.mtot;
    if (o < 320) {
      int t = o / 10, c = o - t * 10;
      float acc = 0.f;
      for (int j = 0; j < mtot; ++j) {
        unsigned wd = sm.l2w[j];
        float wv = sm.u.s5.sW2[c * 1025 + sm.l2i[j]];
        acc += ((wd >> t) & 1u) ? wv : 0.f;
      }
      sm.u.s5.scur[o] = acc;
    }
    __syncthreads();
    if (o < 10) {
      float v = 0.f, cnt2 = 0.f, bias = b2[o];
#pragma unroll
      for (int tt = 0; tt < 32; ++tt) {
        float xc = sm.u.s5.scur[tt * 10 + o] + bias;
        v = v + (xc - v) * 0.5f;
        if (v >= 1.0f) { cnt2 += 1.f; v = 0.f; }
      }
      out[(size_t)b * 10 + o] = cnt2;
    }
  }
}

// ---------------------------------------------------------------------------
extern "C" void kernel_launch(void* const* d_in, const int* in_sizes, int n_in,
                              void* d_out, int out_size, void* d_ws, size_t ws_size,
                              hipStream_t stream) {
  const float* x  = (const float*)d_in[0];   // [512,784]
  const float* W0 = (const float*)d_in[1];   // [1024,784]
  const float* b0 = (const float*)d_in[2];   // [1024]
  const float* W1 = (const float*)d_in[3];   // [1024,1024]
  const float* b1 = (const float*)d_in[4];   // [1024]
  const float* W2 = (const float*)d_in[5];   // [10,1024]
  const float* b2 = (const float*)d_in[6];   // [10]
  float* out = (float*)d_out;                // [512,10]

  char* ws = (char*)d_ws;
  size_t off = 0;
  auto alloc = [&](size_t bytes) -> char* {
    char* p = ws + off;
    off += (bytes + 255) & ~(size_t)255;
    return p;
  };
  float* Cpart = (float*)alloc((size_t)10 * 512 * 1024 * 4);   // 21 MB
  float* W1T   = (float*)alloc((size_t)1024 * 1024 * 4);       // 4.2 MB
  (void)ws_size;

  gemm0t_k<<<1344, 256, 0, stream>>>(x, W0, W1, W1T, Cpart);
  tail_k<<<512, 1024, 0, stream>>>(Cpart, b0, W1T, b1, W2, b2, out);
}